// Round 14
// baseline (3565.319 us; speedup 1.0000x reference)
//
#include <hip/hip_runtime.h>
#include <hip/hip_bf16.h>

// ---------------------------------------------------------------------------
// NeuralODE: 64 Tsit5 steps, f = 128->512->512->128 MLP (tanh, tanh, linear)
// Fused persistent kernel: 256 wgs x 512 threads, each wg owns 32 batch rows.
// Transposed GEMMs (out^T = W^T @ in^T) with mfma_f32_32x32x16_bf16.
// V14 = V13 (champion, 3543us) + per-workgroup K-rotation (L2 de-hot-banking).
//   Ledger: V5 3567 -> V13 3543 (prefetch-across-barriers, +0.7%). All other
//   levers null/negative: bytes (V7/V8), DMA depth (V6 -16%), occupancy
//   (V9 -3x), unroll depth (V10 -21%), barrier-1 (V11), VALU-cut (V12 -4%,
//   VALUBusy 37->30 proved VALU overlapped).
//   UNIFYING THEORY: all 256 wgs read the SAME weight addresses in the SAME
//   order -> at any instant the 32 CUs of an XCD hammer the same few L2
//   lines (hot-banking). Service rate is conflict-bound, not stream-bound.
//   Explains every prior result: more in-flight loads = more pressure on
//   the same banks (V6/V10 regress); more waves same (V9); fewer bytes
//   don't change the hot remainder (V7/V8 null); VALU/barrier cuts don't
//   touch queuing delay (V11/V12).
//   FIX: rotate each wg's K-visit order by blockIdx (accumulation over K is
//   order-independent; fp32 accum rounding shifts ~ulp). L1: (kc+g)&7,
//   L2: (kc+g)&31, L3: kc0+((kk+g)&15). One SALU op per body, zero regs,
//   zero layout change. Prefetches target the rotated first blocks.
//   Null detector (+-2%) => composite L2-latency roofline, declare next.
// fp32 state/accumulators; bf16 only on GEMM operands.
// ---------------------------------------------------------------------------

#define NSTEPS 64

typedef __attribute__((ext_vector_type(8))) short short8;
typedef __attribute__((ext_vector_type(16))) float f32x16;

// LDS layout (bytes)
static constexpr int OFF_YT   = 0;                 // 8 KB: ytmp (B-frags, 8 blocks)
static constexpr int OFF_H    = 8192;              // 32 KB: H (layer1 out, then layer2 out in-place)
static constexpr int KO_S     = 129;               // k row stride (floats), pad vs 128
static constexpr int K_BYTES  = 32 * KO_S * 4;     // 16512 B per k buffer
static constexpr int OFF_K0   = 8192 + 32768;      // five k buffers (k6 reuses K0)
static constexpr int OFF_BIAS = OFF_K0 + 5 * K_BYTES;            // 4608 B
static constexpr int SMEM_BYTES = OFF_BIAS + 1152 * 4;           // = 128128 B

// Tsit5 coefficients
#define C_A21 0.161f
#define C_A31 (-0.008480655492356989f)
#define C_A32 0.335480655492357f
#define C_A41 2.8971530571054935f
#define C_A42 (-6.359448489975075f)
#define C_A43 4.3622954328695815f
#define C_A51 5.325864828439257f
#define C_A52 (-11.748883564062828f)
#define C_A53 7.4955393428898365f
#define C_A54 (-0.09249506636175525f)
#define C_A61 5.86145544294642f
#define C_A62 (-12.92096931784711f)
#define C_A63 8.159367898576159f
#define C_A64 (-0.071584973281401f)
#define C_A65 (-0.028269050394068383f)
#define C_B1 0.09646076681806523f
#define C_B2 0.01f
#define C_B3 0.4798896504144996f
#define C_B4 1.379008574103742f
#define C_B5 (-3.290069515436081f)
#define C_B6 2.324710524099774f

__device__ __forceinline__ float fast_tanh(float x) {
    // tanh(x) = 1 - 2/(exp2(2x*log2e)+1); saturates correctly at +-inf
    float e = __builtin_amdgcn_exp2f(x * 2.88539008177792681472f);
    return 1.0f - 2.0f * __builtin_amdgcn_rcpf(e + 1.0f);
}

__device__ __forceinline__ unsigned int pack2(float a, float b) {
    unsigned short lo = __builtin_bit_cast(unsigned short, __float2bfloat16(a));
    unsigned short hi = __builtin_bit_cast(unsigned short, __float2bfloat16(b));
    return ((unsigned int)hi << 16) | (unsigned int)lo;
}

#define MFMA(a, b, c) __builtin_amdgcn_mfma_f32_32x32x16_bf16((a), (b), (c), 0, 0, 0)

// Write one C tile (f32x16) as tanh(C+bias) into B-frag-layout bf16 LDS buffer.
// Elements group 4-at-a-time into one 8B write (same block, same slot).
__device__ __forceinline__ void store_h(char* smem, int dstOff, const f32x16& acc,
                                        int mt, int q, int lm, const float* bias) {
#pragma unroll
    for (int gblk = 0; gblk < 4; ++gblk) {
        const int r0   = gblk * 4;                            // acc[r0..r0+3]
        const int row0 = 8 * (r0 >> 2) + 4 * q;               // (r0&3)==0
        const int m0   = mt * 32 + row0;
        float v0 = fast_tanh(acc[r0]     + bias[m0]);
        float v1 = fast_tanh(acc[r0 + 1] + bias[m0 + 1]);
        float v2 = fast_tanh(acc[r0 + 2] + bias[m0 + 2]);
        float v3 = fast_tanh(acc[r0 + 3] + bias[m0 + 3]);
        uint2 dw;
        dw.x = pack2(v0, v1);                                 // dword 2q
        dw.y = pack2(v2, v3);                                 // dword 2q+1
        const int b  = 2 * mt + (r0 >> 3);                    // block (k>>4)
        const int s  = lm + 32 * ((r0 >> 2) & 1);             // slot
        const int sp = (s + b) & 63;                          // rotated slot
        *(uint2*)(smem + dstOff + (b << 10) + (sp << 4) + (q << 3)) = dw;
    }
}

// ytmp (B of layer 1): thread t owns (batch row t>>4, d cols 8*(t&15)..+8)
__device__ __forceinline__ void write_ytmp(char* smem, int tid, const float* v) {
    const int b  = (tid & 15) >> 1;
    const int s  = (tid >> 4) + 32 * (tid & 1);
    const int sp = (s + b) & 63;
    uint4 pk;
    pk.x = pack2(v[0], v[1]);
    pk.y = pack2(v[2], v[3]);
    pk.z = pack2(v[4], v[5]);
    pk.w = pack2(v[6], v[7]);
    *(uint4*)(smem + OFF_YT + (b << 10) + (sp << 4)) = pk;
}

// read this thread's 8-element slice of a k buffer
__device__ __forceinline__ void read_k(const char* smem, int koOff, int tid, float* k) {
    const float* ko = (const float*)(smem + koOff);
    const int kb = (tid >> 4) * KO_S + (tid & 15) * 8;
#pragma unroll
    for (int i = 0; i < 8; ++i) k[i] = ko[kb + i];
}

#define LD_YT(kc) (*(const short8*)(smem + OFF_YT + ((kc) << 10) + (((l + (kc)) & 63) << 4)))
#define LD_H(kc)  (*(const short8*)(smem + OFF_H  + ((kc) << 10) + (((l + (kc)) & 63) << 4)))

// One full MLP evaluation: sYtmp -> k buffer at koOff (f32 [32][KO_S])
// rot = per-workgroup K-rotation (de-correlates L2 access order across CUs)
__device__ __forceinline__ void mlp_eval(char* smem, const uint4* __restrict__ wp,
                                         int tid, int rot, int koOff) {
    const int l  = tid & 63;
    const int w  = tid >> 6;
    const int q  = l >> 5;
    const int lm = l & 31;
    const int mt0 = 2 * w, mt1 = mt0 + 1;
    const int mt3  = w & 3;
    const int kc03 = (w >> 2) * 16;
    const float* sb = (const float*)(smem + OFF_BIAS);
    const int r1 = rot & 7, r2 = rot & 31, r3 = rot & 15;

    // prefetch L1 first-visited A-pair (block r1): issued BEFORE the entry
    // barrier; barrier drain absorbs the L2 latency.
    uint4 p1a = wp[(mt0 * 8 + r1) * 64 + l];
    uint4 p1b = wp[(mt1 * 8 + r1) * 64 + l];

    __syncthreads();   // sYtmp ready (also covers bias staging on first call)

    // ---- Layer 1: H[512x32] = tanh(W1t @ Yt + b1), K=128; rotated visit order ----
    uint4 p2a0, p2a1, p2b0, p2b1;   // L2 first two blocks prefetch
    {
        f32x16 acc0, acc1;
#pragma unroll
        for (int i = 0; i < 16; ++i) { acc0[i] = 0.f; acc1[i] = 0.f; }
        // peeled first visit consumes the prefetch (block r1)
        {
            short8 bf = LD_YT(r1);
            acc0 = MFMA(__builtin_bit_cast(short8, p1a), bf, acc0);
            acc1 = MFMA(__builtin_bit_cast(short8, p1b), bf, acc1);
        }
#pragma unroll
        for (int kc = 1; kc < 8; ++kc) {
            const int b = (kc + r1) & 7;
            short8 bf = LD_YT(b);
            uint4 a0 = wp[(mt0 * 8 + b) * 64 + l];
            uint4 a1 = wp[(mt1 * 8 + b) * 64 + l];
            acc0 = MFMA(__builtin_bit_cast(short8, a0), bf, acc0);
            acc1 = MFMA(__builtin_bit_cast(short8, a1), bf, acc1);
        }
        // prefetch L2 blocks r2, r2+1 BEFORE store_h + barrier
        {
            const int b0 = r2, b1 = (r2 + 1) & 31;
            p2a0 = wp[8192 + (mt0 * 32 + b0) * 64 + l];
            p2a1 = wp[8192 + (mt1 * 32 + b0) * 64 + l];
            p2b0 = wp[8192 + (mt0 * 32 + b1) * 64 + l];
            p2b1 = wp[8192 + (mt1 * 32 + b1) * 64 + l];
        }
        store_h(smem, OFF_H, acc0, mt0, q, lm, sb);
        store_h(smem, OFF_H, acc1, mt1, q, lm, sb);
    }
    __syncthreads();

    // ---- Layer 2: H2 = tanh(W2t @ H + b2), K=512; in-place; rotated order ----
    uint4 p3;                        // L3 first-block prefetch
    {
        f32x16 acc0, acc1;
#pragma unroll
        for (int i = 0; i < 16; ++i) { acc0[i] = 0.f; acc1[i] = 0.f; }
        // peeled first two visits consume the prefetch
        {
            const int b0 = r2, b1 = (r2 + 1) & 31;
            short8 bf0 = LD_H(b0);
            short8 bf1 = LD_H(b1);
            acc0 = MFMA(__builtin_bit_cast(short8, p2a0), bf0, acc0);
            acc1 = MFMA(__builtin_bit_cast(short8, p2a1), bf0, acc1);
            acc0 = MFMA(__builtin_bit_cast(short8, p2b0), bf1, acc0);
            acc1 = MFMA(__builtin_bit_cast(short8, p2b1), bf1, acc1);
        }
#pragma unroll 3
        for (int kc = 2; kc < 32; ++kc) {
            const int b = (kc + r2) & 31;
            short8 bf = LD_H(b);
            uint4 a0 = wp[8192 + (mt0 * 32 + b) * 64 + l];
            uint4 a1 = wp[8192 + (mt1 * 32 + b) * 64 + l];
            acc0 = MFMA(__builtin_bit_cast(short8, a0), bf, acc0);
            acc1 = MFMA(__builtin_bit_cast(short8, a1), bf, acc1);
        }
        // prefetch L3 first block BEFORE the WAR barrier + store_h + barrier
        p3 = wp[40960 + (mt3 * 32 + kc03 + r3) * 64 + l];
        __syncthreads();   // all layer-2 reads of H complete before overwrite
        store_h(smem, OFF_H, acc0, mt0, q, lm, sb + 512);
        store_h(smem, OFF_H, acc1, mt1, q, lm, sb + 512);
    }
    __syncthreads();

    // ---- Layer 3: Kt[128x32] = W3t @ H2 + b3 (no tanh), split-K over wave pairs;
    //      rotated visit order within this wave's 16 blocks ----
    {
        f32x16 acc;
#pragma unroll
        for (int i = 0; i < 16; ++i) acc[i] = 0.f;
        // peeled first visit consumes the prefetch (block kc03 + r3)
        {
            short8 bf = LD_H(kc03 + r3);
            acc = MFMA(__builtin_bit_cast(short8, p3), bf, acc);
        }
#pragma unroll 5
        for (int kk = 1; kk < 16; ++kk) {
            const int kc = kc03 + ((kk + r3) & 15);
            short8 bf = LD_H(kc);
            uint4 a = wp[40960 + (mt3 * 32 + kc) * 64 + l];
            acc = MFMA(__builtin_bit_cast(short8, a), bf, acc);
        }
        float* ko = (float*)(smem + koOff);
        if (w < 4) {
#pragma unroll
            for (int r = 0; r < 16; ++r) {
                const int row = (r & 3) + 8 * (r >> 2) + 4 * q;
                const int df  = mt3 * 32 + row;
                ko[lm * KO_S + df] = acc[r] + sb[1024 + df];
            }
        }
        __syncthreads();
        if (w >= 4) {
#pragma unroll
            for (int r = 0; r < 16; ++r) {
                const int row = (r & 3) + 8 * (r >> 2) + 4 * q;
                const int df  = mt3 * 32 + row;
                ko[lm * KO_S + df] += acc[r];
            }
        }
        __syncthreads();   // k buffer complete; safe for all threads to read
    }
}

__global__ __launch_bounds__(512, 1) void ode_kernel(
    const float* __restrict__ y0, const float* __restrict__ ts,
    const float* __restrict__ b1, const float* __restrict__ b2,
    const float* __restrict__ b3, const uint4* __restrict__ wp,
    float* __restrict__ yout)
{
    extern __shared__ __align__(16) char smem[];
    const int tid = threadIdx.x;
    const int g   = blockIdx.x;

    // stage biases into LDS (visible after first barrier inside mlp_eval)
    {
        float* sb = (float*)(smem + OFF_BIAS);
        for (int i = tid; i < 1152; i += 512) {
            float v = (i < 512) ? b1[i] : ((i < 1024) ? b2[i - 512] : b3[i - 1024]);
            sb[i] = v;
        }
    }

    // load this thread's 8 y elements (row-major [B][128])
    const int row = g * 32 + (tid >> 4);
    const int c0  = (tid & 15) * 8;
    float y[8];
    {
        const float4* src = (const float4*)(y0 + row * 128 + c0);
        float4 v0 = src[0], v1 = src[1];
        y[0] = v0.x; y[1] = v0.y; y[2] = v0.z; y[3] = v0.w;
        y[4] = v1.x; y[5] = v1.y; y[6] = v1.z; y[7] = v1.w;
    }

    // scalar dt (wave-uniform; keep in SGPR, apply coefficients as literals)
    const float dt = __builtin_bit_cast(float, __builtin_amdgcn_readfirstlane(
        __builtin_bit_cast(int, (ts[1] - ts[0]) * (1.0f / (float)NSTEPS))));

    float yn[8], yt[8];

    for (int step = 0; step < NSTEPS; ++step) {

        write_ytmp(smem, tid, y);
        mlp_eval(smem, wp, tid, g, OFF_K0);                    // k1 -> K0
        {
            float k1[8];
            read_k(smem, OFF_K0, tid, k1);
#pragma unroll
            for (int i = 0; i < 8; ++i) {
                yn[i] = fmaf(dt, C_B1 * k1[i], y[i]);
                yt[i] = fmaf(dt, C_A21 * k1[i], y[i]);
            }
        }

        write_ytmp(smem, tid, yt);
        mlp_eval(smem, wp, tid, g, OFF_K0 + K_BYTES);          // k2 -> K1
        {
            float k1[8], k2[8];
            read_k(smem, OFF_K0, tid, k1);
            read_k(smem, OFF_K0 + K_BYTES, tid, k2);
#pragma unroll
            for (int i = 0; i < 8; ++i) {
                yn[i] = fmaf(dt, C_B2 * k2[i], yn[i]);
                yt[i] = fmaf(dt, fmaf(C_A32, k2[i], C_A31 * k1[i]), y[i]);
            }
        }

        write_ytmp(smem, tid, yt);
        mlp_eval(smem, wp, tid, g, OFF_K0 + 2 * K_BYTES);      // k3 -> K2
        {
            float k1[8], k2[8], k3[8];
            read_k(smem, OFF_K0, tid, k1);
            read_k(smem, OFF_K0 + K_BYTES, tid, k2);
            read_k(smem, OFF_K0 + 2 * K_BYTES, tid, k3);
#pragma unroll
            for (int i = 0; i < 8; ++i) {
                yn[i] = fmaf(dt, C_B3 * k3[i], yn[i]);
                yt[i] = fmaf(dt, fmaf(C_A43, k3[i],
                             fmaf(C_A42, k2[i], C_A41 * k1[i])), y[i]);
            }
        }

        write_ytmp(smem, tid, yt);
        mlp_eval(smem, wp, tid, g, OFF_K0 + 3 * K_BYTES);      // k4 -> K3
        {
            float k1[8], k2[8], k3[8], k4[8];
            read_k(smem, OFF_K0, tid, k1);
            read_k(smem, OFF_K0 + K_BYTES, tid, k2);
            read_k(smem, OFF_K0 + 2 * K_BYTES, tid, k3);
            read_k(smem, OFF_K0 + 3 * K_BYTES, tid, k4);
#pragma unroll
            for (int i = 0; i < 8; ++i) {
                yn[i] = fmaf(dt, C_B4 * k4[i], yn[i]);
                yt[i] = fmaf(dt, fmaf(C_A54, k4[i], fmaf(C_A53, k3[i],
                             fmaf(C_A52, k2[i], C_A51 * k1[i]))), y[i]);
            }
        }

        write_ytmp(smem, tid, yt);
        mlp_eval(smem, wp, tid, g, OFF_K0 + 4 * K_BYTES);      // k5 -> K4
        {
            float k1[8], k2[8], k3[8], k4[8], k5[8];
            read_k(smem, OFF_K0, tid, k1);
            read_k(smem, OFF_K0 + K_BYTES, tid, k2);
            read_k(smem, OFF_K0 + 2 * K_BYTES, tid, k3);
            read_k(smem, OFF_K0 + 3 * K_BYTES, tid, k4);
            read_k(smem, OFF_K0 + 4 * K_BYTES, tid, k5);
#pragma unroll
            for (int i = 0; i < 8; ++i) {
                yn[i] = fmaf(dt, C_B5 * k5[i], yn[i]);
                yt[i] = fmaf(dt, fmaf(C_A65, k5[i], fmaf(C_A64, k4[i],
                             fmaf(C_A63, k3[i], fmaf(C_A62, k2[i],
                             C_A61 * k1[i])))), y[i]);
            }
        }

        write_ytmp(smem, tid, yt);
        mlp_eval(smem, wp, tid, g, OFF_K0);                    // k6 -> K0 (k1 dead)
        {
            float k6[8];
            read_k(smem, OFF_K0, tid, k6);
#pragma unroll
            for (int i = 0; i < 8; ++i) {
                y[i] = fmaf(dt, C_B6 * k6[i], yn[i]);
            }
        }
    }

    // store final state (f32)
    {
        float4 o0, o1;
        o0.x = y[0]; o0.y = y[1]; o0.z = y[2]; o0.w = y[3];
        o1.x = y[4]; o1.y = y[5]; o1.z = y[6]; o1.w = y[7];
        float4* dst = (float4*)(yout + row * 128 + c0);
        dst[0] = o0; dst[1] = o1;
    }
}

// ---------------------------------------------------------------------------
// Pack W1,W2,W3 (f32 row-major [K][M]) into bf16 A-fragment blocks for the
// transposed GEMMs: block (mt,kc) is 1 KB; lane l holds A[m=mt*32+(l&31)]
// [k=kc*16+8*(l>>5)+j], j=0..7, at block + l*16 + j*2.
// ---------------------------------------------------------------------------
__global__ void pack_weights(const float* __restrict__ W1, const float* __restrict__ W2,
                             const float* __restrict__ W3, unsigned short* __restrict__ out)
{
    const int tid = blockIdx.x * blockDim.x + threadIdx.x;   // 0..393215
    float v;
    if (tid < 65536) {                    // W1t [512 x 128], blocks: mt 0..15, kc 0..7
        const int e = tid, blk = e >> 9, wi = e & 511, l = wi >> 3, j = wi & 7;
        const int mt = blk >> 3, kc = blk & 7;
        const int m = mt * 32 + (l & 31);
        const int k = kc * 16 + 8 * (l >> 5) + j;
        v = W1[k * 512 + m];
    } else if (tid < 327680) {            // W2t [512 x 512], blocks: mt 0..15, kc 0..31
        const int e = tid - 65536, blk = e >> 9, wi = e & 511, l = wi >> 3, j = wi & 7;
        const int mt = blk >> 5, kc = blk & 31;
        const int m = mt * 32 + (l & 31);
        const int k = kc * 16 + 8 * (l >> 5) + j;
        v = W2[k * 512 + m];
    } else {                              // W3t [128 x 512], blocks: mt 0..3, kc 0..31
        const int e = tid - 327680, blk = e >> 9, wi = e & 511, l = wi >> 3, j = wi & 7;
        const int mt = blk >> 5, kc = blk & 31;
        const int m = mt * 32 + (l & 31);
        const int k = kc * 16 + 8 * (l >> 5) + j;
        v = W3[k * 128 + m];
    }
    out[tid] = __builtin_bit_cast(unsigned short, __float2bfloat16(v));
}

extern "C" void kernel_launch(void* const* d_in, const int* in_sizes, int n_in,
                              void* d_out, int out_size, void* d_ws, size_t ws_size,
                              hipStream_t stream)
{
    const float* y0 = (const float*)d_in[0];
    const float* ts = (const float*)d_in[1];
    const float* W1 = (const float*)d_in[2];
    const float* b1 = (const float*)d_in[3];
    const float* W2 = (const float*)d_in[4];
    const float* b2 = (const float*)d_in[5];
    const float* W3 = (const float*)d_in[6];
    const float* b3 = (const float*)d_in[7];
    unsigned short* wp = (unsigned short*)d_ws;   // 786432 B of packed bf16 weights

    pack_weights<<<1536, 256, 0, stream>>>(W1, W2, W3, wp);

    (void)hipFuncSetAttribute((const void*)ode_kernel,
                              hipFuncAttributeMaxDynamicSharedMemorySize, SMEM_BYTES);
    ode_kernel<<<256, 512, SMEM_BYTES, stream>>>(y0, ts, b1, b2, b3,
                                                 (const uint4*)wp, (float*)d_out);
}

// Round 15
// 3529.092 us; speedup vs baseline: 1.0103x; 1.0103x over previous
//
#include <hip/hip_runtime.h>
#include <hip/hip_bf16.h>

// ---------------------------------------------------------------------------
// NeuralODE: 64 Tsit5 steps, f = 128->512->512->128 MLP (tanh, tanh, linear)
// Fused persistent kernel: 256 wgs x 512 threads, each wg owns 32 batch rows.
// Transposed GEMMs (out^T = W^T @ in^T) with mfma_f32_32x32x16_bf16.
// V15 = V13 (champion, 3543us; rotation of V14 reverted — null) + 32KB W2
//       slab feeding ONLY layer-2's already-peeled head (kc 0,1).
//   Ledger: V5 3567 -> V13 3543. Falsified: DMA depth (V6), loop-split slab
//   (V7 spill), reg-cache (V8 remat), occupancy (V9), unroll depth (V10),
//   barrier count (V11), VALU (V12), L2 access-order (V14).
//   REMAINING HYPOTHESIS: per-CU global-load byte rate (~35 B/cyc measured,
//   768KB/eval / 22.2k cyc) is the binding port limit. Never cleanly tested:
//   V7 spilled (loop split), V8 rematerialized. This version cuts bytes
//   -8.3% with ZERO loop-structure change and LOWER register pressure:
//   the peeled head's 4 global prefetches become 4 LDS reads from a
//   once-staged slab (W2 kc 0,1 x 16 mt = 32 KB; LDS 160896 <= 163840).
//   Read: dur -8% => byte-bound confirmed, pursue bytes next.
//         null    => bytes ruled out cleanly; declare composite roofline.
//   Detectors: WRITE_SIZE MB-scale or FETCH GB-scale => spill => revert.
// fp32 state/accumulators; bf16 only on GEMM operands.
// ---------------------------------------------------------------------------

#define NSTEPS 64

typedef __attribute__((ext_vector_type(8))) short short8;
typedef __attribute__((ext_vector_type(16))) float f32x16;

// LDS layout (bytes)
static constexpr int OFF_YT   = 0;                 // 8 KB: ytmp (B-frags, 8 blocks)
static constexpr int OFF_H    = 8192;              // 32 KB: H (layer1 out, then layer2 out in-place)
static constexpr int KO_S     = 129;               // k row stride (floats), pad vs 128
static constexpr int K_BYTES  = 32 * KO_S * 4;     // 16512 B per k buffer
static constexpr int OFF_K0   = 8192 + 32768;      // five k buffers (k6 reuses K0)
static constexpr int OFF_BIAS = OFF_K0 + 5 * K_BYTES;            // 4608 B
static constexpr int OFF_W2S  = OFF_BIAS + 1152 * 4;             // 32 KB W2 slab (kc 0,1)
static constexpr int SMEM_BYTES = OFF_W2S + 32 * 1024;           // = 160896 B

// Tsit5 coefficients
#define C_A21 0.161f
#define C_A31 (-0.008480655492356989f)
#define C_A32 0.335480655492357f
#define C_A41 2.8971530571054935f
#define C_A42 (-6.359448489975075f)
#define C_A43 4.3622954328695815f
#define C_A51 5.325864828439257f
#define C_A52 (-11.748883564062828f)
#define C_A53 7.4955393428898365f
#define C_A54 (-0.09249506636175525f)
#define C_A61 5.86145544294642f
#define C_A62 (-12.92096931784711f)
#define C_A63 8.159367898576159f
#define C_A64 (-0.071584973281401f)
#define C_A65 (-0.028269050394068383f)
#define C_B1 0.09646076681806523f
#define C_B2 0.01f
#define C_B3 0.4798896504144996f
#define C_B4 1.379008574103742f
#define C_B5 (-3.290069515436081f)
#define C_B6 2.324710524099774f

__device__ __forceinline__ float fast_tanh(float x) {
    // tanh(x) = 1 - 2/(exp2(2x*log2e)+1); saturates correctly at +-inf
    float e = __builtin_amdgcn_exp2f(x * 2.88539008177792681472f);
    return 1.0f - 2.0f * __builtin_amdgcn_rcpf(e + 1.0f);
}

__device__ __forceinline__ unsigned int pack2(float a, float b) {
    unsigned short lo = __builtin_bit_cast(unsigned short, __float2bfloat16(a));
    unsigned short hi = __builtin_bit_cast(unsigned short, __float2bfloat16(b));
    return ((unsigned int)hi << 16) | (unsigned int)lo;
}

#define MFMA(a, b, c) __builtin_amdgcn_mfma_f32_32x32x16_bf16((a), (b), (c), 0, 0, 0)

// Write one C tile (f32x16) as tanh(C+bias) into B-frag-layout bf16 LDS buffer.
// Elements group 4-at-a-time into one 8B write (same block, same slot).
__device__ __forceinline__ void store_h(char* smem, int dstOff, const f32x16& acc,
                                        int mt, int q, int lm, const float* bias) {
#pragma unroll
    for (int gblk = 0; gblk < 4; ++gblk) {
        const int r0   = gblk * 4;                            // acc[r0..r0+3]
        const int row0 = 8 * (r0 >> 2) + 4 * q;               // (r0&3)==0
        const int m0   = mt * 32 + row0;
        float v0 = fast_tanh(acc[r0]     + bias[m0]);
        float v1 = fast_tanh(acc[r0 + 1] + bias[m0 + 1]);
        float v2 = fast_tanh(acc[r0 + 2] + bias[m0 + 2]);
        float v3 = fast_tanh(acc[r0 + 3] + bias[m0 + 3]);
        uint2 dw;
        dw.x = pack2(v0, v1);                                 // dword 2q
        dw.y = pack2(v2, v3);                                 // dword 2q+1
        const int b  = 2 * mt + (r0 >> 3);                    // block (k>>4)
        const int s  = lm + 32 * ((r0 >> 2) & 1);             // slot
        const int sp = (s + b) & 63;                          // rotated slot
        *(uint2*)(smem + dstOff + (b << 10) + (sp << 4) + (q << 3)) = dw;
    }
}

// ytmp (B of layer 1): thread t owns (batch row t>>4, d cols 8*(t&15)..+8)
__device__ __forceinline__ void write_ytmp(char* smem, int tid, const float* v) {
    const int b  = (tid & 15) >> 1;
    const int s  = (tid >> 4) + 32 * (tid & 1);
    const int sp = (s + b) & 63;
    uint4 pk;
    pk.x = pack2(v[0], v[1]);
    pk.y = pack2(v[2], v[3]);
    pk.z = pack2(v[4], v[5]);
    pk.w = pack2(v[6], v[7]);
    *(uint4*)(smem + OFF_YT + (b << 10) + (sp << 4)) = pk;
}

// read this thread's 8-element slice of a k buffer
__device__ __forceinline__ void read_k(const char* smem, int koOff, int tid, float* k) {
    const float* ko = (const float*)(smem + koOff);
    const int kb = (tid >> 4) * KO_S + (tid & 15) * 8;
#pragma unroll
    for (int i = 0; i < 8; ++i) k[i] = ko[kb + i];
}

#define LD_YT(kc) (*(const short8*)(smem + OFF_YT + ((kc) << 10) + (((l + (kc)) & 63) << 4)))
#define LD_H(kc)  (*(const short8*)(smem + OFF_H  + ((kc) << 10) + (((l + (kc)) & 63) << 4)))

// One full MLP evaluation: sYtmp -> k buffer at koOff (f32 [32][KO_S])
__device__ __forceinline__ void mlp_eval(char* smem, const uint4* __restrict__ wp,
                                         int tid, int koOff) {
    const int l  = tid & 63;
    const int w  = tid >> 6;
    const int q  = l >> 5;
    const int lm = l & 31;
    const int mt0 = 2 * w, mt1 = mt0 + 1;
    const int mt3  = w & 3;
    const int kc03 = (w >> 2) * 16;
    const float* sb = (const float*)(smem + OFF_BIAS);

    // prefetch L1 kc=0 A-pair: issued BEFORE the entry barrier; barrier
    // drain absorbs the L2 latency.
    uint4 p1a = wp[(mt0 * 8) * 64 + l];
    uint4 p1b = wp[(mt1 * 8) * 64 + l];

    __syncthreads();   // sYtmp ready (also covers bias/slab staging on first call)

    // ---- Layer 1: H[512x32] = tanh(W1t @ Yt + b1), K=128; A streamed (L2) ----
    {
        f32x16 acc0, acc1;
#pragma unroll
        for (int i = 0; i < 16; ++i) { acc0[i] = 0.f; acc1[i] = 0.f; }
        // peeled kc=0 consumes the prefetch
        {
            short8 bf = LD_YT(0);
            acc0 = MFMA(__builtin_bit_cast(short8, p1a), bf, acc0);
            acc1 = MFMA(__builtin_bit_cast(short8, p1b), bf, acc1);
        }
#pragma unroll
        for (int kc = 1; kc < 8; ++kc) {
            short8 bf = LD_YT(kc);
            uint4 a0 = wp[(mt0 * 8 + kc) * 64 + l];
            uint4 a1 = wp[(mt1 * 8 + kc) * 64 + l];
            acc0 = MFMA(__builtin_bit_cast(short8, a0), bf, acc0);
            acc1 = MFMA(__builtin_bit_cast(short8, a1), bf, acc1);
        }
        store_h(smem, OFF_H, acc0, mt0, q, lm, sb);
        store_h(smem, OFF_H, acc1, mt1, q, lm, sb);
    }
    __syncthreads();

    // ---- Layer 2: H2 = tanh(W2t @ H + b2), K=512; in-place into H ----
    uint4 p3;                        // L3 kk=0 prefetch
    {
        f32x16 acc0, acc1;
#pragma unroll
        for (int i = 0; i < 16; ++i) { acc0[i] = 0.f; acc1[i] = 0.f; }
        // peeled kc=0,1: A comes from the persistent LDS slab (zero global
        // bytes, zero cross-barrier prefetch registers)
        {
            short8 bf0 = LD_H(0);
            short8 bf1 = LD_H(1);
            short8 a00 = *(const short8*)(smem + OFF_W2S + ((mt0 * 2 + 0) << 10) + (l << 4));
            short8 a10 = *(const short8*)(smem + OFF_W2S + ((mt1 * 2 + 0) << 10) + (l << 4));
            short8 a01 = *(const short8*)(smem + OFF_W2S + ((mt0 * 2 + 1) << 10) + (l << 4));
            short8 a11 = *(const short8*)(smem + OFF_W2S + ((mt1 * 2 + 1) << 10) + (l << 4));
            acc0 = MFMA(a00, bf0, acc0);
            acc1 = MFMA(a10, bf0, acc1);
            acc0 = MFMA(a01, bf1, acc0);
            acc1 = MFMA(a11, bf1, acc1);
        }
#pragma unroll 3
        for (int kc = 2; kc < 32; ++kc) {
            short8 bf = LD_H(kc);
            uint4 a0 = wp[8192 + (mt0 * 32 + kc) * 64 + l];
            uint4 a1 = wp[8192 + (mt1 * 32 + kc) * 64 + l];
            acc0 = MFMA(__builtin_bit_cast(short8, a0), bf, acc0);
            acc1 = MFMA(__builtin_bit_cast(short8, a1), bf, acc1);
        }
        // prefetch L3 kk=0 BEFORE the WAR barrier + store_h + barrier
        p3 = wp[40960 + (mt3 * 32 + kc03) * 64 + l];
        __syncthreads();   // all layer-2 reads of H complete before overwrite
        store_h(smem, OFF_H, acc0, mt0, q, lm, sb + 512);
        store_h(smem, OFF_H, acc1, mt1, q, lm, sb + 512);
    }
    __syncthreads();

    // ---- Layer 3: Kt[128x32] = W3t @ H2 + b3 (no tanh), split-K over wave pairs;
    //      A streamed from global (L2-resident); result -> k buffer ----
    {
        f32x16 acc;
#pragma unroll
        for (int i = 0; i < 16; ++i) acc[i] = 0.f;
        // peeled kk=0 consumes the prefetch
        {
            short8 bf = LD_H(kc03);
            acc = MFMA(__builtin_bit_cast(short8, p3), bf, acc);
        }
#pragma unroll 5
        for (int kk = 1; kk < 16; ++kk) {
            const int kc = kc03 + kk;
            short8 bf = LD_H(kc);
            uint4 a = wp[40960 + (mt3 * 32 + kc) * 64 + l];
            acc = MFMA(__builtin_bit_cast(short8, a), bf, acc);
        }
        float* ko = (float*)(smem + koOff);
        if (w < 4) {
#pragma unroll
            for (int r = 0; r < 16; ++r) {
                const int row = (r & 3) + 8 * (r >> 2) + 4 * q;
                const int df  = mt3 * 32 + row;
                ko[lm * KO_S + df] = acc[r] + sb[1024 + df];
            }
        }
        __syncthreads();
        if (w >= 4) {
#pragma unroll
            for (int r = 0; r < 16; ++r) {
                const int row = (r & 3) + 8 * (r >> 2) + 4 * q;
                const int df  = mt3 * 32 + row;
                ko[lm * KO_S + df] += acc[r];
            }
        }
        __syncthreads();   // k buffer complete; safe for all threads to read
    }
}

__global__ __launch_bounds__(512, 1) void ode_kernel(
    const float* __restrict__ y0, const float* __restrict__ ts,
    const float* __restrict__ b1, const float* __restrict__ b2,
    const float* __restrict__ b3, const uint4* __restrict__ wp,
    float* __restrict__ yout)
{
    extern __shared__ __align__(16) char smem[];
    const int tid = threadIdx.x;
    const int g   = blockIdx.x;

    // stage biases into LDS (visible after first barrier inside mlp_eval)
    {
        float* sb = (float*)(smem + OFF_BIAS);
        for (int i = tid; i < 1152; i += 512) {
            float v = (i < 512) ? b1[i] : ((i < 1024) ? b2[i - 512] : b3[i - 1024]);
            sb[i] = v;
        }
    }

    // stage W2 slab: kc 0,1 for all 16 mt -> 32 blocks of 1 KB (block = mt*2+kc)
    {
        for (int i = tid; i < 32 * 64; i += 512) {
            const int blk = i >> 6, li = i & 63;
            const int mt = blk >> 1, kc = blk & 1;
            *(uint4*)(smem + OFF_W2S + (blk << 10) + (li << 4)) =
                wp[8192 + (mt * 32 + kc) * 64 + li];
        }
    }

    // load this thread's 8 y elements (row-major [B][128])
    const int row = g * 32 + (tid >> 4);
    const int c0  = (tid & 15) * 8;
    float y[8];
    {
        const float4* src = (const float4*)(y0 + row * 128 + c0);
        float4 v0 = src[0], v1 = src[1];
        y[0] = v0.x; y[1] = v0.y; y[2] = v0.z; y[3] = v0.w;
        y[4] = v1.x; y[5] = v1.y; y[6] = v1.z; y[7] = v1.w;
    }

    // scalar dt (wave-uniform; keep in SGPR, apply coefficients as literals)
    const float dt = __builtin_bit_cast(float, __builtin_amdgcn_readfirstlane(
        __builtin_bit_cast(int, (ts[1] - ts[0]) * (1.0f / (float)NSTEPS))));

    float yn[8], yt[8];

    for (int step = 0; step < NSTEPS; ++step) {

        write_ytmp(smem, tid, y);
        mlp_eval(smem, wp, tid, OFF_K0);                       // k1 -> K0
        {
            float k1[8];
            read_k(smem, OFF_K0, tid, k1);
#pragma unroll
            for (int i = 0; i < 8; ++i) {
                yn[i] = fmaf(dt, C_B1 * k1[i], y[i]);
                yt[i] = fmaf(dt, C_A21 * k1[i], y[i]);
            }
        }

        write_ytmp(smem, tid, yt);
        mlp_eval(smem, wp, tid, OFF_K0 + K_BYTES);             // k2 -> K1
        {
            float k1[8], k2[8];
            read_k(smem, OFF_K0, tid, k1);
            read_k(smem, OFF_K0 + K_BYTES, tid, k2);
#pragma unroll
            for (int i = 0; i < 8; ++i) {
                yn[i] = fmaf(dt, C_B2 * k2[i], yn[i]);
                yt[i] = fmaf(dt, fmaf(C_A32, k2[i], C_A31 * k1[i]), y[i]);
            }
        }

        write_ytmp(smem, tid, yt);
        mlp_eval(smem, wp, tid, OFF_K0 + 2 * K_BYTES);         // k3 -> K2
        {
            float k1[8], k2[8], k3[8];
            read_k(smem, OFF_K0, tid, k1);
            read_k(smem, OFF_K0 + K_BYTES, tid, k2);
            read_k(smem, OFF_K0 + 2 * K_BYTES, tid, k3);
#pragma unroll
            for (int i = 0; i < 8; ++i) {
                yn[i] = fmaf(dt, C_B3 * k3[i], yn[i]);
                yt[i] = fmaf(dt, fmaf(C_A43, k3[i],
                             fmaf(C_A42, k2[i], C_A41 * k1[i])), y[i]);
            }
        }

        write_ytmp(smem, tid, yt);
        mlp_eval(smem, wp, tid, OFF_K0 + 3 * K_BYTES);         // k4 -> K3
        {
            float k1[8], k2[8], k3[8], k4[8];
            read_k(smem, OFF_K0, tid, k1);
            read_k(smem, OFF_K0 + K_BYTES, tid, k2);
            read_k(smem, OFF_K0 + 2 * K_BYTES, tid, k3);
            read_k(smem, OFF_K0 + 3 * K_BYTES, tid, k4);
#pragma unroll
            for (int i = 0; i < 8; ++i) {
                yn[i] = fmaf(dt, C_B4 * k4[i], yn[i]);
                yt[i] = fmaf(dt, fmaf(C_A54, k4[i], fmaf(C_A53, k3[i],
                             fmaf(C_A52, k2[i], C_A51 * k1[i]))), y[i]);
            }
        }

        write_ytmp(smem, tid, yt);
        mlp_eval(smem, wp, tid, OFF_K0 + 4 * K_BYTES);         // k5 -> K4
        {
            float k1[8], k2[8], k3[8], k4[8], k5[8];
            read_k(smem, OFF_K0, tid, k1);
            read_k(smem, OFF_K0 + K_BYTES, tid, k2);
            read_k(smem, OFF_K0 + 2 * K_BYTES, tid, k3);
            read_k(smem, OFF_K0 + 3 * K_BYTES, tid, k4);
            read_k(smem, OFF_K0 + 4 * K_BYTES, tid, k5);
#pragma unroll
            for (int i = 0; i < 8; ++i) {
                yn[i] = fmaf(dt, C_B5 * k5[i], yn[i]);
                yt[i] = fmaf(dt, fmaf(C_A65, k5[i], fmaf(C_A64, k4[i],
                             fmaf(C_A63, k3[i], fmaf(C_A62, k2[i],
                             C_A61 * k1[i])))), y[i]);
            }
        }

        write_ytmp(smem, tid, yt);
        mlp_eval(smem, wp, tid, OFF_K0);                       // k6 -> K0 (k1 dead)
        {
            float k6[8];
            read_k(smem, OFF_K0, tid, k6);
#pragma unroll
            for (int i = 0; i < 8; ++i) {
                y[i] = fmaf(dt, C_B6 * k6[i], yn[i]);
            }
        }
    }

    // store final state (f32)
    {
        float4 o0, o1;
        o0.x = y[0]; o0.y = y[1]; o0.z = y[2]; o0.w = y[3];
        o1.x = y[4]; o1.y = y[5]; o1.z = y[6]; o1.w = y[7];
        float4* dst = (float4*)(yout + row * 128 + c0);
        dst[0] = o0; dst[1] = o1;
    }
}

// ---------------------------------------------------------------------------
// Pack W1,W2,W3 (f32 row-major [K][M]) into bf16 A-fragment blocks for the
// transposed GEMMs: block (mt,kc) is 1 KB; lane l holds A[m=mt*32+(l&31)]
// [k=kc*16+8*(l>>5)+j], j=0..7, at block + l*16 + j*2.
// ---------------------------------------------------------------------------
__global__ void pack_weights(const float* __restrict__ W1, const float* __restrict__ W2,
                             const float* __restrict__ W3, unsigned short* __restrict__ out)
{
    const int tid = blockIdx.x * blockDim.x + threadIdx.x;   // 0..393215
    float v;
    if (tid < 65536) {                    // W1t [512 x 128], blocks: mt 0..15, kc 0..7
        const int e = tid, blk = e >> 9, wi = e & 511, l = wi >> 3, j = wi & 7;
        const int mt = blk >> 3, kc = blk & 7;
        const int m = mt * 32 + (l & 31);
        const int k = kc * 16 + 8 * (l >> 5) + j;
        v = W1[k * 512 + m];
    } else if (tid < 327680) {            // W2t [512 x 512], blocks: mt 0..15, kc 0..31
        const int e = tid - 65536, blk = e >> 9, wi = e & 511, l = wi >> 3, j = wi & 7;
        const int mt = blk >> 5, kc = blk & 31;
        const int m = mt * 32 + (l & 31);
        const int k = kc * 16 + 8 * (l >> 5) + j;
        v = W2[k * 512 + m];
    } else {                              // W3t [128 x 512], blocks: mt 0..3, kc 0..31
        const int e = tid - 327680, blk = e >> 9, wi = e & 511, l = wi >> 3, j = wi & 7;
        const int mt = blk >> 5, kc = blk & 31;
        const int m = mt * 32 + (l & 31);
        const int k = kc * 16 + 8 * (l >> 5) + j;
        v = W3[k * 128 + m];
    }
    out[tid] = __builtin_bit_cast(unsigned short, __float2bfloat16(v));
}

extern "C" void kernel_launch(void* const* d_in, const int* in_sizes, int n_in,
                              void* d_out, int out_size, void* d_ws, size_t ws_size,
                              hipStream_t stream)
{
    const float* y0 = (const float*)d_in[0];
    const float* ts = (const float*)d_in[1];
    const float* W1 = (const float*)d_in[2];
    const float* b1 = (const float*)d_in[3];
    const float* W2 = (const float*)d_in[4];
    const float* b2 = (const float*)d_in[5];
    const float* W3 = (const float*)d_in[6];
    const float* b3 = (const float*)d_in[7];
    unsigned short* wp = (unsigned short*)d_ws;   // 786432 B of packed bf16 weights

    pack_weights<<<1536, 256, 0, stream>>>(W1, W2, W3, wp);

    (void)hipFuncSetAttribute((const void*)ode_kernel,
                              hipFuncAttributeMaxDynamicSharedMemorySize, SMEM_BYTES);
    ode_kernel<<<256, 512, SMEM_BYTES, stream>>>(y0, ts, b1, b2, b3,
                                                 (const uint4*)wp, (float*)d_out);
}